// Round 2
// baseline (178.192 us; speedup 1.0000x reference)
//
#include <hip/hip_runtime.h>
#include <stdint.h>

typedef __bf16 bf16;
typedef __attribute__((ext_vector_type(2))) __bf16 bf16x2;
typedef __attribute__((ext_vector_type(4))) __bf16 bf16x4;
typedef __attribute__((ext_vector_type(8))) __bf16 bf16x8;
typedef __attribute__((ext_vector_type(4))) float f32x4;
typedef __attribute__((ext_vector_type(16))) float f32x16;

#define LOG2E_OVER_8 0.18033688011112042f  // log2(e)/sqrt(64), folded into q

#if __has_builtin(__builtin_amdgcn_exp2f)
#define EXP2(x) __builtin_amdgcn_exp2f(x)   // raw v_exp_f32: D = 2^S0
#else
#define EXP2(x) exp2f(x)
#endif

// async global->LDS, 16B/lane; LDS dest = wave-uniform base + lane*16
__device__ __forceinline__ void gl_lds16(const bf16* g, bf16* l) {
  __builtin_amdgcn_global_load_lds(
      (const __attribute__((address_space(1))) void*)g,
      (__attribute__((address_space(3))) void*)l, 16, 0, 0);
}
// counted waits: keep younger DMA groups in flight across the barrier (T4).
#define WAIT_VM0_BARRIER() asm volatile("s_waitcnt vmcnt(0)\n\ts_barrier" ::: "memory")
#define WAIT_VM4_BARRIER() asm volatile("s_waitcnt vmcnt(4)\n\ts_barrier" ::: "memory")

__device__ __forceinline__ uint32_t pack2(float a, float b) {
  union { bf16x2 v; uint32_t u; } z;
  z.v[0] = (bf16)a; z.v[1] = (bf16)b;
  return z.u;
}

// v_permlane32_swap_b32 a, b : a.hi31 <-> b.lo31
//   after: a = {a.lo, b.lo}, b = {a.hi, b.hi}
__device__ __forceinline__ void pl32swap(uint32_t& a, uint32_t& b) {
  asm("v_permlane32_swap_b32 %0, %1" : "+v"(a), "+v"(b));
}

// ---------------- fused fp32 -> bf16 convert (x, qkv_w, out_w) ----------------
#define N_X  (4096 * 1024)
#define N_WQ (3072 * 1024)
#define N_WO (1024 * 1024)
__global__ __launch_bounds__(256) void cvt3_kernel(const float* __restrict__ x,
                                                   const float* __restrict__ wq,
                                                   const float* __restrict__ wo,
                                                   bf16* __restrict__ d) {
  int i = (blockIdx.x * 256 + threadIdx.x) * 8;
  const float* s;
  if (i < N_X) s = x + i;
  else if (i < N_X + N_WQ) s = wq + (i - N_X);
  else s = wo + (i - N_X - N_WQ);
  float4 a = *(const float4*)s;
  float4 b = *(const float4*)(s + 4);
  bf16x8 o;
  o[0] = (bf16)a.x; o[1] = (bf16)a.y; o[2] = (bf16)a.z; o[3] = (bf16)a.w;
  o[4] = (bf16)b.x; o[5] = (bf16)b.y; o[6] = (bf16)b.z; o[7] = (bf16)b.w;
  *(bf16x8*)(d + i) = o;
}

// ---------------- NT GEMM + XCD supertiling ----------------
// EPI=0: 128x128 tile, BK=32, grid 768, TRIPLE-buffered LDS (49KB, 3 blocks/CU),
//        2-deep prefetch with counted vmcnt(4) waits (never drain to 0 in loop),
//        scatter epilogue via LDS -> q,k,vT.
// EPI=1: 64x128 tile, BK=64 (2 chunks/barrier, 16 barriers), grid 512,
//        double-buffered, fp32 out + bias. LDS 48KB -> 3 blocks/CU.
// LDS layout: chunks of 32 cols: [kc][rows][32] (keeps proven bank pattern).
template <int EPI>
__global__ __launch_bounds__(256, 3) void gemm_bt(
    const bf16* __restrict__ A, const bf16* __restrict__ Bw,
    const float* __restrict__ bias,
    bf16* __restrict__ qo, bf16* __restrict__ ko, bf16* __restrict__ vTo,
    float* __restrict__ outF) {
  constexpr int MT = EPI ? 64 : 128;
  constexpr int MI = MT / 32;
  constexpr int BK = EPI ? 64 : 32;
  constexpr int NC = BK / 32;               // 32-col chunks per barrier
  constexpr int NIT = 1024 / BK;
  constexpr int ASZ = MT * BK;              // elems per A buffer
  constexpr int BSZ = 128 * BK;
  constexpr int NBUF = EPI ? 2 : 3;
  constexpr int RS = 136;
  constexpr int SME0 = NBUF * ASZ + NBUF * BSZ;
  constexpr int SME = EPI ? SME0 : (SME0 > 128 * RS ? SME0 : 128 * RS);
  __shared__ __attribute__((aligned(16))) bf16 smem[SME];

  int bx, by;
  {
    const int f = blockIdx.x;
    const int xcd = f & 7, idx = f >> 3;
    if constexpr (EPI == 0) { by = xcd * 4 + (idx & 3); bx = idx >> 2; }
    else                    { by = xcd * 8 + (idx & 7); bx = idx >> 3; }
  }

  const int t = threadIdx.x;
  const int L = t & 63;
  const int li = L & 15;
  const int qd = L >> 4;
  const int w = t >> 6;
  const int wm = (w >> 1) * (MT / 2);
  const int wn = (w & 1) * 64;
  const int bm0 = by * MT;
  const int bn0 = bx * 128;
  const int r_st = t >> 2;         // 0..63
  const int c_st = (t & 3) * 8;    // within a 32-col chunk

  const bf16* Ab = A + (size_t)bm0 * 1024;
  const bf16* Bb = Bw + (size_t)bn0 * 1024;

  auto issue = [&](int k0, int bi) {
    bf16* As_ = smem + bi * ASZ;
    bf16* Bs_ = smem + NBUF * ASZ + bi * BSZ;
#pragma unroll
    for (int kc = 0; kc < NC; ++kc) {
      const int kk = k0 + kc * 32;
      // A chunk: MT rows x 32 cols
      gl_lds16(Ab + (size_t)r_st * 1024 + kk + c_st, As_ + kc * MT * 32 + t * 8);
      if constexpr (MT == 128)
        gl_lds16(Ab + (size_t)(r_st + 64) * 1024 + kk + c_st,
                 As_ + kc * MT * 32 + (t + 256) * 8);
      // B chunk: 128 rows x 32 cols
      gl_lds16(Bb + (size_t)r_st * 1024 + kk + c_st, Bs_ + kc * 4096 + t * 8);
      gl_lds16(Bb + (size_t)(r_st + 64) * 1024 + kk + c_st,
               Bs_ + kc * 4096 + (t + 256) * 8);
    }
  };

  f32x4 acc[MI][4] = {};

  auto compute_tile = [&](const bf16* Ac, const bf16* Bc) {
#pragma unroll
    for (int kc = 0; kc < NC; ++kc) {
      const bf16* Ak = Ac + kc * MT * 32;
      const bf16* Bk = Bc + kc * 4096;
      bf16x8 af[MI], bfr[4];
#pragma unroll
      for (int mi = 0; mi < MI; ++mi)
        af[mi] = *(const bf16x8*)(Ak + (wm + mi * 16 + li) * 32 + qd * 8);
#pragma unroll
      for (int ni = 0; ni < 4; ++ni)
        bfr[ni] = *(const bf16x8*)(Bk + (wn + ni * 16 + li) * 32 + qd * 8);
#pragma unroll
      for (int mi = 0; mi < MI; ++mi)
#pragma unroll
        for (int ni = 0; ni < 4; ++ni)
          acc[mi][ni] = __builtin_amdgcn_mfma_f32_16x16x32_bf16(
              af[mi], bfr[ni], acc[mi][ni], 0, 0, 0);
    }
  };

  if constexpr (EPI == 0) {
    // 2-deep prefetch, counted waits. Per issue: 4 gl_lds16/thread.
    issue(0, 0);
    issue(BK, 1);
    for (int it = 0; it < NIT; ++it) {
      if (it < NIT - 1) WAIT_VM4_BARRIER();   // tile it ready; it+1 in flight
      else              WAIT_VM0_BARRIER();   // last tile: full drain
      if (it < NIT - 2) issue((it + 2) * BK, (it + 2) % 3);
      compute_tile(smem + (it % 3) * ASZ, smem + NBUF * ASZ + (it % 3) * BSZ);
    }
  } else {
    issue(0, 0);
    for (int it = 0; it < NIT; ++it) {
      WAIT_VM0_BARRIER();
      if (it < NIT - 1) issue((it + 1) * BK, (it + 1) & 1);
      compute_tile(smem + (it & 1) * ASZ, smem + NBUF * ASZ + (it & 1) * BSZ);
    }
  }

  if constexpr (EPI == 0) {
    const int which = bn0 >> 10;  // 0:q 1:k 2:v
    __syncthreads();
    bf16* Ct = smem;
    if (which == 2) {
#pragma unroll
      for (int mi = 0; mi < MI; ++mi) {
        const int m_l = wm + mi * 16 + qd * 4;
#pragma unroll
        for (int ni = 0; ni < 4; ++ni) {
          const int n_l = wn + ni * 16 + li;
          const float bi = bias[bn0 + n_l];
          bf16x4 pk;
#pragma unroll
          for (int r = 0; r < 4; ++r) pk[r] = (bf16)(acc[mi][ni][r] + bi);
          *(bf16x4*)(Ct + n_l * RS + m_l) = pk;
        }
      }
    } else {
      const float sc = (which == 0) ? LOG2E_OVER_8 : 1.0f;
#pragma unroll
      for (int mi = 0; mi < MI; ++mi) {
        const int m_l = wm + mi * 16 + qd * 4;
#pragma unroll
        for (int ni = 0; ni < 4; ++ni) {
          const int n_l = wn + ni * 16 + li;
          const float bi = bias[bn0 + n_l];
#pragma unroll
          for (int r = 0; r < 4; ++r)
            Ct[(m_l + r) * RS + n_l] = (bf16)((acc[mi][ni][r] + bi) * sc);
        }
      }
    }
    __syncthreads();
    const int jr = t >> 4;
    const int jc = t & 15;
#pragma unroll
    for (int pass = 0; pass < 8; ++pass) {
      const int row = pass * 16 + jr;
      bf16x8 vv = *(const bf16x8*)(Ct + row * RS + jc * 8);
      if (which == 2) {
        const int n_g = bn0 + row;
        const int hh = (n_g >> 6) & 15, dd = n_g & 63;
        const int bb = bm0 >> 11;
        const int s_b = (bm0 & 2047) + jc * 8;
        *(bf16x8*)(vTo + ((size_t)(bb * 16 + hh) * 64 + dd) * 2048 + s_b) = vv;
      } else {
        const int m_g = bm0 + row;
        const int bb = m_g >> 11, ss = m_g & 2047;
        const int n_g = bn0 + jc * 8;
        const int hh = (n_g >> 6) & 15, dd = n_g & 63;
        bf16* dst = (which == 0 ? qo : ko);
        *(bf16x8*)(dst + ((size_t)(bb * 16 + hh) * 2048 + ss) * 64 + dd) = vv;
      }
    }
  } else {
#pragma unroll
    for (int mi = 0; mi < MI; ++mi) {
      const int m_g = bm0 + wm + mi * 16 + qd * 4;
#pragma unroll
      for (int ni = 0; ni < 4; ++ni) {
        const int n_g = bn0 + wn + ni * 16 + li;
        const float bi = bias[n_g];
#pragma unroll
        for (int r = 0; r < 4; ++r)
          outF[(size_t)(m_g + r) * 1024 + n_g] = acc[mi][ni][r] + bi;
      }
    }
  }
}

// ---------------- flash attention: R12: counted-vmcnt split K/V waits ----------------
// grid 512 (1D) XCD-swizzled. Block = 4 waves, 128 q rows; wave owns 32.
// K/V LDS dbuf (64KB) with XOR-swizzled staging. Per it2 the two 64-key tiles
// are phase-fused. Waits are COUNTED (T4): vmcnt(4)+barrier for K (V still in
// flight), QK^T, issue K(next), vmcnt(4)+barrier for V (K(next) stays in
// flight through softmax+PV), issue V(next). No full drain in the main loop.
__global__ __launch_bounds__(256, 2) void attn_fwd(
    const bf16* __restrict__ Q, const bf16* __restrict__ K,
    const bf16* __restrict__ VT, bf16* __restrict__ AO) {
  __shared__ __attribute__((aligned(16))) bf16 Ks[2 * 8192];  // [buf][tile*4096]
  __shared__ __attribute__((aligned(16))) bf16 Vs[2 * 8192];
  const int t = threadIdx.x;   // 0..255
  const int L = t & 63;
  const int m31 = L & 31;
  const int hi = L >> 5;
  const int w = t >> 6;        // 0..3

  const int lid = blockIdx.x;  // 0..511
  const int bh_ = ((lid & 7) << 2) + (lid >> 7);  // 4 bh per XCD
  const int qb = (lid >> 3) & 15;                 // 16 q-tiles of 128
  const int b = bh_ >> 4, h = bh_ & 15;
  const size_t bh = (size_t)(b * 16 + h);

  const bf16* Qp = Q + bh * 2048 * 64;
  const bf16* Kp = K + bh * 2048 * 64;
  const bf16* Vp = VT + bh * 64 * 2048;
  const int q0 = qb * 128 + w * 32;

  // Q B-frags: qf[s] = Q[q0+m31][s*16 + hi*8 .. +7]
  bf16x8 qf[4];
#pragma unroll
  for (int s = 0; s < 4; ++s)
    qf[s] = *(const bf16x8*)(Qp + (size_t)(q0 + m31) * 64 + s * 16 + hi * 8);

  // 4 independent accumulator chains: [dt][tile-parity], merged at end
  f32x16 acc[2][2] = {};
  // 4 partial row-sums (per tile x kt2 group) -> short dependency chains
  float ls[4] = {0.f, 0.f, 0.f, 0.f};

  // staging: phys 16B chunk p = row*8 + (cc ^ (row&7)); 256 thr, 2 rows each
  const int srow = t >> 3;                 // 0..31 (+32 on r=1)
  const int scc = (t & 7) ^ (srow & 7);    // (srow+32)&7 == srow&7
  // 4 gl_lds16/thread per group; K group always issued before V group so
  // vmcnt(4) at the top of an iteration selects the K group as the oldest.
  auto issueK = [&](int it2, int bi) {
#pragma unroll
    for (int tile = 0; tile < 2; ++tile) {
      const int kt = it2 * 2 + tile;
      const bf16* Kt = Kp + (size_t)kt * 4096;
      bf16* Kd = Ks + bi * 8192 + tile * 4096;
#pragma unroll
      for (int r = 0; r < 2; ++r)
        gl_lds16(Kt + (srow + 32 * r) * 64 + scc * 8, Kd + (t + 256 * r) * 8);
    }
  };
  auto issueV = [&](int it2, int bi) {
#pragma unroll
    for (int tile = 0; tile < 2; ++tile) {
      const int kt = it2 * 2 + tile;
      const bf16* Vt = Vp + kt * 64;
      bf16* Vd = Vs + bi * 8192 + tile * 4096;
#pragma unroll
      for (int r = 0; r < 2; ++r)
        gl_lds16(Vt + (size_t)(srow + 32 * r) * 2048 + scc * 8, Vd + (t + 256 * r) * 8);
    }
  };

  const int rlow = m31 & 7;
  issueK(0, 0);
  issueV(0, 0);
  for (int it2 = 0; it2 < 16; ++it2) {
    WAIT_VM4_BARRIER();  // K(cur) in LDS; V(cur) still in flight
    const bf16* Kc0 = Ks + (it2 & 1) * 8192;
    const bf16* Vc0 = Vs + (it2 & 1) * 8192;

    // ---- phase 1: St = K.Q^T for BOTH tiles (4 independent MFMA chains) ----
    f32x16 st[2][2];
#pragma unroll
    for (int tile = 0; tile < 2; ++tile) {
      const bf16* Kc = Kc0 + tile * 4096;
#pragma unroll
      for (int kt2 = 0; kt2 < 2; ++kt2) {
        f32x16 z = {};
#pragma unroll
        for (int s = 0; s < 4; ++s) {
          bf16x8 kf = *(const bf16x8*)(
              Kc + ((kt2 * 32 + m31) * 8 + ((2 * s + hi) ^ rlow)) * 8);
          z = __builtin_amdgcn_mfma_f32_32x32x16_bf16(kf, qf[s], z, 0, 0, 0);
        }
        st[tile][kt2] = z;
      }
    }

    // next K tiles: in flight through softmax + PV (safe: all waves passed
    // the barrier above, hence finished QK^T(it2-1) which last read this buf)
    if (it2 < 15) issueK(it2 + 1, (it2 + 1) & 1);

    if (it2 < 15) WAIT_VM4_BARRIER();  // V(cur) in LDS; K(next) in flight
    else          WAIT_VM0_BARRIER();  // last iteration: drain

    // next V tiles: in flight through PV + next QK^T (safe: all waves passed
    // the barrier above, hence finished PV(it2-1) which last read this buf)
    if (it2 < 15) issueV(it2 + 1, (it2 + 1) & 1);

    // ---- phase 2: p = 2^s, pack to bf16 pairs, permlane exchange (both tiles) ----
    union FU { uint32_t u[4]; bf16x8 v; };
    FU af[2][2][2];  // [tile][kt2][u]
#pragma unroll
    for (int tile = 0; tile < 2; ++tile)
#pragma unroll
      for (int kt2 = 0; kt2 < 2; ++kt2) {
        uint32_t pk[8];
        float lsl = 0.f;
#pragma unroll
        for (int j = 0; j < 8; ++j) {
          float a = EXP2(st[tile][kt2][2 * j]);
          float c = EXP2(st[tile][kt2][2 * j + 1]);
          lsl += a + c;
          pk[j] = pack2(a, c);
        }
        ls[tile * 2 + kt2] += lsl;
        pl32swap(pk[0], pk[2]);
        pl32swap(pk[1], pk[3]);
        pl32swap(pk[4], pk[6]);
        pl32swap(pk[5], pk[7]);
        af[tile][kt2][0].u[0] = pk[0]; af[tile][kt2][0].u[1] = pk[1];
        af[tile][kt2][0].u[2] = pk[2]; af[tile][kt2][0].u[3] = pk[3];
        af[tile][kt2][1].u[0] = pk[4]; af[tile][kt2][1].u[1] = pk[5];
        af[tile][kt2][1].u[2] = pk[6]; af[tile][kt2][1].u[3] = pk[7];
      }

    // ---- phase 3: O += P @ V, 4 independent chains acc[dt][tile] ----
#pragma unroll
    for (int dt = 0; dt < 2; ++dt)
#pragma unroll
      for (int tile = 0; tile < 2; ++tile) {
        const bf16* Vc = Vc0 + tile * 4096;
#pragma unroll
        for (int kt2 = 0; kt2 < 2; ++kt2)
#pragma unroll
          for (int u = 0; u < 2; ++u) {
            bf16x8 vf = *(const bf16x8*)(
                Vc + ((dt * 32 + m31) * 8 + ((kt2 * 4 + u * 2 + hi) ^ rlow)) * 8);
            acc[dt][tile] = __builtin_amdgcn_mfma_f32_32x32x16_bf16(
                af[tile][kt2][u].v, vf, acc[dt][tile], 0, 0, 0);
          }
      }
  }

  // merge tile-parity accumulators + full row sum for q=m31
  f32x16 accf[2];
#pragma unroll
  for (int dt = 0; dt < 2; ++dt) accf[dt] = acc[dt][0] + acc[dt][1];
  float lsum = (ls[0] + ls[1]) + (ls[2] + ls[3]);
  lsum += __shfl_xor(lsum, 32);
  const float inv = 1.f / lsum;

  // redistribute inv to C-layout rows, normalize, store
#pragma unroll
  for (int r = 0; r < 16; ++r) {
    const int qrow = (r & 3) + 8 * (r >> 2) + 4 * hi;
    const float invq = __shfl(inv, qrow);
    const size_t base = ((size_t)b * 2048 + q0 + qrow) * 1024 + h * 64 + m31;
    AO[base] = (bf16)(accf[0][r] * invq);
    AO[base + 32] = (bf16)(accf[1][r] * invq);
  }
}

// ---------------- launch ----------------
extern "C" void kernel_launch(void* const* d_in, const int* in_sizes, int n_in,
                              void* d_out, int out_size, void* d_ws, size_t ws_size,
                              hipStream_t stream) {
  const float* x = (const float*)d_in[0];
  const float* qkvw = (const float*)d_in[1];
  const float* qkvb = (const float*)d_in[2];
  const float* outw = (const float*)d_in[3];
  const float* outb = (const float*)d_in[4];
  float* out = (float*)d_out;

  bf16* xb = (bf16*)d_ws;                     // 4096*1024
  bf16* wq = xb + (size_t)N_X;                // 3072*1024
  bf16* wo = wq + (size_t)N_WQ;               // 1024*1024
  bf16* q = wo + (size_t)N_WO;                // 32*2048*64
  bf16* kk = q + (size_t)2 * 16 * 2048 * 64;
  bf16* vT = kk + (size_t)2 * 16 * 2048 * 64;
  bf16* attn = xb;                            // alias (xb dead after GEMM1)

  cvt3_kernel<<<4096, 256, 0, stream>>>(x, qkvw, outw, xb);

  gemm_bt<0><<<768, 256, 0, stream>>>(xb, wq, qkvb, q, kk, vT, nullptr);
  attn_fwd<<<512, 256, 0, stream>>>(q, kk, vT, attn);
  gemm_bt<1><<<512, 256, 0, stream>>>(attn, wo, outb, nullptr, nullptr, nullptr, out);
}

// Round 3
// 175.666 us; speedup vs baseline: 1.0144x; 1.0144x over previous
//
#include <hip/hip_runtime.h>
#include <stdint.h>

typedef __bf16 bf16;
typedef __attribute__((ext_vector_type(2))) __bf16 bf16x2;
typedef __attribute__((ext_vector_type(4))) __bf16 bf16x4;
typedef __attribute__((ext_vector_type(8))) __bf16 bf16x8;
typedef __attribute__((ext_vector_type(4))) float f32x4;
typedef __attribute__((ext_vector_type(16))) float f32x16;

#define LOG2E_OVER_8 0.18033688011112042f  // log2(e)/sqrt(64), folded into q

#if __has_builtin(__builtin_amdgcn_exp2f)
#define EXP2(x) __builtin_amdgcn_exp2f(x)   // raw v_exp_f32: D = 2^S0
#else
#define EXP2(x) exp2f(x)
#endif

// async global->LDS, 16B/lane; LDS dest = wave-uniform base + lane*16
__device__ __forceinline__ void gl_lds16(const bf16* g, bf16* l) {
  __builtin_amdgcn_global_load_lds(
      (const __attribute__((address_space(1))) void*)g,
      (__attribute__((address_space(3))) void*)l, 16, 0, 0);
}
// wait own loads, then sync -> everyone's loads are in LDS; DMA issued after
// this line stays in flight through the whole compute phase.
// (R12's counted-vmcnt 2-barrier split measured WORSE: barrier cost > drain
// savings with 2 blocks/CU cross-covering. Single drain barrier is best.)
#define WAIT_VM0_BARRIER() asm volatile("s_waitcnt vmcnt(0)\n\ts_barrier" ::: "memory")

__device__ __forceinline__ uint32_t pack2(float a, float b) {
  union { bf16x2 v; uint32_t u; } z;
  z.v[0] = (bf16)a; z.v[1] = (bf16)b;
  return z.u;
}

// v_permlane32_swap_b32 a, b : a.hi31 <-> b.lo31
//   after: a = {a.lo, b.lo}, b = {a.hi, b.hi}
__device__ __forceinline__ void pl32swap(uint32_t& a, uint32_t& b) {
  asm("v_permlane32_swap_b32 %0, %1" : "+v"(a), "+v"(b));
}

// ---------------- fused fp32 -> bf16 convert (x, qkv_w, out_w) ----------------
#define N_X  (4096 * 1024)
#define N_WQ (3072 * 1024)
#define N_WO (1024 * 1024)
__global__ __launch_bounds__(256) void cvt3_kernel(const float* __restrict__ x,
                                                   const float* __restrict__ wq,
                                                   const float* __restrict__ wo,
                                                   bf16* __restrict__ d) {
  int i = (blockIdx.x * 256 + threadIdx.x) * 8;
  const float* s;
  if (i < N_X) s = x + i;
  else if (i < N_X + N_WQ) s = wq + (i - N_X);
  else s = wo + (i - N_X - N_WQ);
  float4 a = *(const float4*)s;
  float4 b = *(const float4*)(s + 4);
  bf16x8 o;
  o[0] = (bf16)a.x; o[1] = (bf16)a.y; o[2] = (bf16)a.z; o[3] = (bf16)a.w;
  o[4] = (bf16)b.x; o[5] = (bf16)b.y; o[6] = (bf16)b.z; o[7] = (bf16)b.w;
  *(bf16x8*)(d + i) = o;
}

// ---------------- NT GEMM, single-barrier prefetch + XCD supertiling ----------------
// EPI=0: 128x128 tile, BK=32, grid 768, scatter epilogue via LDS -> q,k,vT
// EPI=1: 64x128 tile, BK=64 (2 chunks/barrier, 16 barriers), grid 512,
//        fp32 out + bias. LDS 48KB -> still 3 blocks/CU.
// LDS layout: chunks of 32 cols: [kc][rows][32] (keeps proven bank pattern).
// (R12 triple-buffer + counted vmcnt on EPI=0 was neutral-to-negative; reverted.)
template <int EPI>
__global__ __launch_bounds__(256, 3) void gemm_bt(
    const bf16* __restrict__ A, const bf16* __restrict__ Bw,
    const float* __restrict__ bias,
    bf16* __restrict__ qo, bf16* __restrict__ ko, bf16* __restrict__ vTo,
    float* __restrict__ outF) {
  constexpr int MT = EPI ? 64 : 128;
  constexpr int MI = MT / 32;
  constexpr int BK = EPI ? 64 : 32;
  constexpr int NC = BK / 32;               // 32-col chunks per barrier
  constexpr int NIT = 1024 / BK;
  constexpr int ASZ = MT * BK;              // elems per A buffer
  constexpr int BSZ = 128 * BK;
  constexpr int RS = 136;
  constexpr int SME0 = 2 * ASZ + 2 * BSZ;
  constexpr int SME = EPI ? SME0 : (SME0 > 128 * RS ? SME0 : 128 * RS);
  __shared__ __attribute__((aligned(16))) bf16 smem[SME];

  int bx, by;
  {
    const int f = blockIdx.x;
    const int xcd = f & 7, idx = f >> 3;
    if constexpr (EPI == 0) { by = xcd * 4 + (idx & 3); bx = idx >> 2; }
    else                    { by = xcd * 8 + (idx & 7); bx = idx >> 3; }
  }

  const int t = threadIdx.x;
  const int L = t & 63;
  const int li = L & 15;
  const int qd = L >> 4;
  const int w = t >> 6;
  const int wm = (w >> 1) * (MT / 2);
  const int wn = (w & 1) * 64;
  const int bm0 = by * MT;
  const int bn0 = bx * 128;
  const int r_st = t >> 2;         // 0..63
  const int c_st = (t & 3) * 8;    // within a 32-col chunk

  const bf16* Ab = A + (size_t)bm0 * 1024;
  const bf16* Bb = Bw + (size_t)bn0 * 1024;

  auto issue = [&](int k0, int bi) {
    bf16* As_ = smem + bi * ASZ;
    bf16* Bs_ = smem + 2 * ASZ + bi * BSZ;
#pragma unroll
    for (int kc = 0; kc < NC; ++kc) {
      const int kk = k0 + kc * 32;
      // A chunk: MT rows x 32 cols
      gl_lds16(Ab + (size_t)r_st * 1024 + kk + c_st, As_ + kc * MT * 32 + t * 8);
      if constexpr (MT == 128)
        gl_lds16(Ab + (size_t)(r_st + 64) * 1024 + kk + c_st,
                 As_ + kc * MT * 32 + (t + 256) * 8);
      // B chunk: 128 rows x 32 cols
      gl_lds16(Bb + (size_t)r_st * 1024 + kk + c_st, Bs_ + kc * 4096 + t * 8);
      gl_lds16(Bb + (size_t)(r_st + 64) * 1024 + kk + c_st,
               Bs_ + kc * 4096 + (t + 256) * 8);
    }
  };

  f32x4 acc[MI][4] = {};
  issue(0, 0);
  for (int it = 0; it < NIT; ++it) {
    WAIT_VM0_BARRIER();
    if (it < NIT - 1) issue((it + 1) * BK, (it + 1) & 1);
    const bf16* Ac = smem + (it & 1) * ASZ;
    const bf16* Bc = smem + 2 * ASZ + (it & 1) * BSZ;
#pragma unroll
    for (int kc = 0; kc < NC; ++kc) {
      const bf16* Ak = Ac + kc * MT * 32;
      const bf16* Bk = Bc + kc * 4096;
      bf16x8 af[MI], bfr[4];
#pragma unroll
      for (int mi = 0; mi < MI; ++mi)
        af[mi] = *(const bf16x8*)(Ak + (wm + mi * 16 + li) * 32 + qd * 8);
#pragma unroll
      for (int ni = 0; ni < 4; ++ni)
        bfr[ni] = *(const bf16x8*)(Bk + (wn + ni * 16 + li) * 32 + qd * 8);
#pragma unroll
      for (int mi = 0; mi < MI; ++mi)
#pragma unroll
        for (int ni = 0; ni < 4; ++ni)
          acc[mi][ni] = __builtin_amdgcn_mfma_f32_16x16x32_bf16(
              af[mi], bfr[ni], acc[mi][ni], 0, 0, 0);
    }
  }

  if constexpr (EPI == 0) {
    const int which = bn0 >> 10;  // 0:q 1:k 2:v
    __syncthreads();
    bf16* Ct = smem;
    if (which == 2) {
#pragma unroll
      for (int mi = 0; mi < MI; ++mi) {
        const int m_l = wm + mi * 16 + qd * 4;
#pragma unroll
        for (int ni = 0; ni < 4; ++ni) {
          const int n_l = wn + ni * 16 + li;
          const float bi = bias[bn0 + n_l];
          bf16x4 pk;
#pragma unroll
          for (int r = 0; r < 4; ++r) pk[r] = (bf16)(acc[mi][ni][r] + bi);
          *(bf16x4*)(Ct + n_l * RS + m_l) = pk;
        }
      }
    } else {
      const float sc = (which == 0) ? LOG2E_OVER_8 : 1.0f;
#pragma unroll
      for (int mi = 0; mi < MI; ++mi) {
        const int m_l = wm + mi * 16 + qd * 4;
#pragma unroll
        for (int ni = 0; ni < 4; ++ni) {
          const int n_l = wn + ni * 16 + li;
          const float bi = bias[bn0 + n_l];
#pragma unroll
          for (int r = 0; r < 4; ++r)
            Ct[(m_l + r) * RS + n_l] = (bf16)((acc[mi][ni][r] + bi) * sc);
        }
      }
    }
    __syncthreads();
    const int jr = t >> 4;
    const int jc = t & 15;
#pragma unroll
    for (int pass = 0; pass < 8; ++pass) {
      const int row = pass * 16 + jr;
      bf16x8 vv = *(const bf16x8*)(Ct + row * RS + jc * 8);
      if (which == 2) {
        const int n_g = bn0 + row;
        const int hh = (n_g >> 6) & 15, dd = n_g & 63;
        const int bb = bm0 >> 11;
        const int s_b = (bm0 & 2047) + jc * 8;
        *(bf16x8*)(vTo + ((size_t)(bb * 16 + hh) * 64 + dd) * 2048 + s_b) = vv;
      } else {
        const int m_g = bm0 + row;
        const int bb = m_g >> 11, ss = m_g & 2047;
        const int n_g = bn0 + jc * 8;
        const int hh = (n_g >> 6) & 15, dd = n_g & 63;
        bf16* dst = (which == 0 ? qo : ko);
        *(bf16x8*)(dst + ((size_t)(bb * 16 + hh) * 2048 + ss) * 64 + dd) = vv;
      }
    }
  } else {
#pragma unroll
    for (int mi = 0; mi < MI; ++mi) {
      const int m_g = bm0 + wm + mi * 16 + qd * 4;
#pragma unroll
      for (int ni = 0; ni < 4; ++ni) {
        const int n_g = bn0 + wn + ni * 16 + li;
        const float bi = bias[n_g];
#pragma unroll
        for (int r = 0; r < 4; ++r)
          outF[(size_t)(m_g + r) * 1024 + n_g] = acc[mi][ni][r] + bi;
      }
    }
  }
}

// ---------------- flash attention: R13: group-pipelined phases + setprio ----------------
// grid 512 (1D) XCD-swizzled. Block = 4 waves, 128 q rows; wave owns 32.
// R11 schedule (single vmcnt(0)+barrier per it2, K/V dbuf 64KB, XOR-swizzled
// staging) -- proven best. NEW: the 4 (tile,kt2) groups are software-pipelined
// in source order  QKT0 QKT1 SM0 QKT2 PV0 SM1 QKT3 PV1 SM2 PV2 SM3 PV3  so
// softmax VALU/trans work always sits between independent MFMA+LDS clusters
// (T15 structure), and each MFMA cluster is wrapped in s_setprio(1) (T5).
__global__ __launch_bounds__(256, 2) void attn_fwd(
    const bf16* __restrict__ Q, const bf16* __restrict__ K,
    const bf16* __restrict__ VT, bf16* __restrict__ AO) {
  __shared__ __attribute__((aligned(16))) bf16 Ks[2 * 8192];  // [buf][tile*4096]
  __shared__ __attribute__((aligned(16))) bf16 Vs[2 * 8192];
  const int t = threadIdx.x;   // 0..255
  const int L = t & 63;
  const int m31 = L & 31;
  const int hi = L >> 5;
  const int w = t >> 6;        // 0..3

  const int lid = blockIdx.x;  // 0..511
  const int bh_ = ((lid & 7) << 2) + (lid >> 7);  // 4 bh per XCD
  const int qb = (lid >> 3) & 15;                 // 16 q-tiles of 128
  const int b = bh_ >> 4, h = bh_ & 15;
  const size_t bh = (size_t)(b * 16 + h);

  const bf16* Qp = Q + bh * 2048 * 64;
  const bf16* Kp = K + bh * 2048 * 64;
  const bf16* Vp = VT + bh * 64 * 2048;
  const int q0 = qb * 128 + w * 32;

  // Q B-frags: qf[s] = Q[q0+m31][s*16 + hi*8 .. +7]
  bf16x8 qf[4];
#pragma unroll
  for (int s = 0; s < 4; ++s)
    qf[s] = *(const bf16x8*)(Qp + (size_t)(q0 + m31) * 64 + s * 16 + hi * 8);

  // 4 independent accumulator chains: [dt][tile], merged at end
  f32x16 acc[2][2] = {};
  // 4 partial row-sums (per tile x kt2 group) -> short dependency chains
  float ls[4] = {0.f, 0.f, 0.f, 0.f};

  // staging: phys 16B chunk p = row*8 + (cc ^ (row&7)); 256 thr, 2 rows each
  const int srow = t >> 3;                 // 0..31 (+32 on r=1)
  const int scc = (t & 7) ^ (srow & 7);    // (srow+32)&7 == srow&7
  auto issue = [&](int it2, int bi) {
#pragma unroll
    for (int tile = 0; tile < 2; ++tile) {
      const int kt = it2 * 2 + tile;
      const bf16* Kt = Kp + (size_t)kt * 4096;
      const bf16* Vt = Vp + kt * 64;
      bf16* Kd = Ks + bi * 8192 + tile * 4096;
      bf16* Vd = Vs + bi * 8192 + tile * 4096;
#pragma unroll
      for (int r = 0; r < 2; ++r) {
        gl_lds16(Kt + (srow + 32 * r) * 64 + scc * 8, Kd + (t + 256 * r) * 8);
        gl_lds16(Vt + (size_t)(srow + 32 * r) * 2048 + scc * 8, Vd + (t + 256 * r) * 8);
      }
    }
  };

  const int rlow = m31 & 7;
  union FU { uint32_t u[4]; bf16x8 v; };

  issue(0, 0);
  for (int it2 = 0; it2 < 16; ++it2) {
    WAIT_VM0_BARRIER();
    if (it2 < 15) issue(it2 + 1, (it2 + 1) & 1);
    const bf16* Kc0 = Ks + (it2 & 1) * 8192;
    const bf16* Vc0 = Vs + (it2 & 1) * 8192;

    // QKT: St = K.Q^T 32x32 tile for group (tile,kt2); 4 chained MFMA
    auto QKT = [&](int tile, int kt2) -> f32x16 {
      const bf16* Kc = Kc0 + tile * 4096;
      f32x16 z = {};
      __builtin_amdgcn_s_setprio(1);
#pragma unroll
      for (int s = 0; s < 4; ++s) {
        bf16x8 kf = *(const bf16x8*)(
            Kc + ((kt2 * 32 + m31) * 8 + ((2 * s + hi) ^ rlow)) * 8);
        z = __builtin_amdgcn_mfma_f32_32x32x16_bf16(kf, qf[s], z, 0, 0, 0);
      }
      __builtin_amdgcn_s_setprio(0);
      return z;
    };

    // SM: p = 2^s, pack to bf16 pairs, permlane exchange -> 2 A-frags
    auto SM = [&](const f32x16& st, int gi, FU* afp) {
      uint32_t pk[8];
      float lsl = 0.f;
#pragma unroll
      for (int j = 0; j < 8; ++j) {
        float a = EXP2(st[2 * j]);
        float c = EXP2(st[2 * j + 1]);
        lsl += a + c;
        pk[j] = pack2(a, c);
      }
      ls[gi] += lsl;
      pl32swap(pk[0], pk[2]);
      pl32swap(pk[1], pk[3]);
      pl32swap(pk[4], pk[6]);
      pl32swap(pk[5], pk[7]);
      afp[0].u[0] = pk[0]; afp[0].u[1] = pk[1];
      afp[0].u[2] = pk[2]; afp[0].u[3] = pk[3];
      afp[1].u[0] = pk[4]; afp[1].u[1] = pk[5];
      afp[1].u[2] = pk[6]; afp[1].u[3] = pk[7];
    };

    // PV: O += P(tile,kt2) @ V ; 4 MFMA into acc[0..1][tile]
    auto PV = [&](int tile, int kt2, const FU* afp) {
      const bf16* Vc = Vc0 + tile * 4096;
      __builtin_amdgcn_s_setprio(1);
#pragma unroll
      for (int dt = 0; dt < 2; ++dt)
#pragma unroll
        for (int u = 0; u < 2; ++u) {
          bf16x8 vf = *(const bf16x8*)(
              Vc + ((dt * 32 + m31) * 8 + ((kt2 * 4 + u * 2 + hi) ^ rlow)) * 8);
          acc[dt][tile] = __builtin_amdgcn_mfma_f32_32x32x16_bf16(
              afp[u].v, vf, acc[dt][tile], 0, 0, 0);
        }
      __builtin_amdgcn_s_setprio(0);
    };

    // group-pipelined emission: g0=(0,0) g1=(0,1) g2=(1,0) g3=(1,1)
    FU A0[2], A1[2], A2[2], A3[2];
    f32x16 st0 = QKT(0, 0);
    f32x16 st1 = QKT(0, 1);
    SM(st0, 0, A0);
    f32x16 st2 = QKT(1, 0);
    PV(0, 0, A0);
    SM(st1, 1, A1);
    f32x16 st3 = QKT(1, 1);
    PV(0, 1, A1);
    SM(st2, 2, A2);
    PV(1, 0, A2);
    SM(st3, 3, A3);
    PV(1, 1, A3);
  }

  // merge tile accumulators + full row sum for q=m31
  f32x16 accf[2];
#pragma unroll
  for (int dt = 0; dt < 2; ++dt) accf[dt] = acc[dt][0] + acc[dt][1];
  float lsum = (ls[0] + ls[1]) + (ls[2] + ls[3]);
  lsum += __shfl_xor(lsum, 32);
  const float inv = 1.f / lsum;

  // redistribute inv to C-layout rows, normalize, store
#pragma unroll
  for (int r = 0; r < 16; ++r) {
    const int qrow = (r & 3) + 8 * (r >> 2) + 4 * hi;
    const float invq = __shfl(inv, qrow);
    const size_t base = ((size_t)b * 2048 + q0 + qrow) * 1024 + h * 64 + m31;
    AO[base] = (bf16)(accf[0][r] * invq);
    AO[base + 32] = (bf16)(accf[1][r] * invq);
  }
}

// ---------------- launch ----------------
extern "C" void kernel_launch(void* const* d_in, const int* in_sizes, int n_in,
                              void* d_out, int out_size, void* d_ws, size_t ws_size,
                              hipStream_t stream) {
  const float* x = (const float*)d_in[0];
  const float* qkvw = (const float*)d_in[1];
  const float* qkvb = (const float*)d_in[2];
  const float* outw = (const float*)d_in[3];
  const float* outb = (const float*)d_in[4];
  float* out = (float*)d_out;

  bf16* xb = (bf16*)d_ws;                     // 4096*1024
  bf16* wq = xb + (size_t)N_X;                // 3072*1024
  bf16* wo = wq + (size_t)N_WQ;               // 1024*1024
  bf16* q = wo + (size_t)N_WO;                // 32*2048*64
  bf16* kk = q + (size_t)2 * 16 * 2048 * 64;
  bf16* vT = kk + (size_t)2 * 16 * 2048 * 64;
  bf16* attn = xb;                            // alias (xb dead after GEMM1)

  cvt3_kernel<<<4096, 256, 0, stream>>>(x, qkvw, outw, xb);

  gemm_bt<0><<<768, 256, 0, stream>>>(xb, wq, qkvb, q, kk, vT, nullptr);
  attn_fwd<<<512, 256, 0, stream>>>(q, kk, vT, attn);
  gemm_bt<1><<<512, 256, 0, stream>>>(attn, wo, outb, nullptr, nullptr, nullptr, out);
}